// Round 20
// baseline (51.105 us; speedup 1.0000x reference)
//
#include <hip/hip_runtime.h>
#include <stdint.h>
#include <float.h>

// Chamfer distance, B=4, N=M=4096, 3D fp32.
// Outputs (flat, float32): [0] loss, [1..16384] idx12 (float), [16385..32768] idx21.
//
// SEMANTIC CONTRACT (validated R14-R19, absmax 0.0 — do not change):
//   d in f64: d = fma(dx,dx, fma(dy,dy, dz*dz)), dx = x - bx (f64-promoted f32)
//   pick = smallest index j with d_j <= fma(TOL_K(dir), a2 + b2_j, dmin)
//     (a2, b2_j in f64 from promoted f32 coords)
//   K12 = 0.6*2^-23, K21 = 0.   dmin = exact f64 min.
//   Prefilter (R16-proven 2x margin): survivor iff
//     d32 <= fma(2e-7, a2f+b2f_j, me), me = m*(1+2e-6), m = global f32 min.
//   Split skip (R18-validated): skip iff splitmin > (me + 7e-7*a2f)*(1+4e-6).
//
// R20: cd_select was gather-bound (32 lanes x 16KB-strided splitmin reads =
// 64MB scattered cross-XCD traffic ~20us). Block-cooperative select: 256 thr
// own 64 consecutive points; coalesced 32x64 panel load -> padded LDS;
// survivor (point,split) pairs into LDS queue, processed load-balanced by all
// 4 waves; dmin/pick combined via LDS atomicMin (order-independent). Loss
// partials per block (fixed butterfly) -> finalize kernel + dminArr removed.
// All filter/contract formulas byte-identical to R18/R19.

constexpr int B_ = 4;
constexpr int N_ = 4096;
constexpr int PTS = 256;
constexpr int PPT = 8;
constexpr int TILES = N_ / (PTS * PPT);  // 2
constexpr int JSPLIT = 32;
constexpr int CHUNK = N_ / JSPLIT;       // 128
constexpr double EPS32 = 1.1920928955078125e-7;  // 2^-23
constexpr double TOL_K12 = 0.6 * EPS32;
constexpr double TOL_K21 = 0.0;
constexpr double BETA_ = 1.0;
constexpr double GAMMA_ = 1.0;
constexpr double DELTA_ = 0.0;

// grid: (TILES*B_*2, JSPLIT)
__global__ __launch_bounds__(256) void cd_min32(
        const float* __restrict__ xyz1, const float* __restrict__ xyz2,
        unsigned int* __restrict__ splitmin) {
    const int tile  = blockIdx.x % TILES;
    const int b     = (blockIdx.x / TILES) % B_;
    const int dir   = blockIdx.x / (TILES * B_);
    const int split = blockIdx.y;
    const float* A  = dir ? xyz2 : xyz1;
    const float* Bc = dir ? xyz1 : xyz2;

    __shared__ float4 s[CHUNK];          // 2 KiB
    const float* bbase = Bc + ((size_t)b * N_ + (size_t)split * CHUNK) * 3;
    if (threadIdx.x < CHUNK) {
        int j = threadIdx.x;
        s[j] = make_float4(bbase[3 * j], bbase[3 * j + 1], bbase[3 * j + 2], 0.f);
    }
    __syncthreads();

    float px[PPT], py[PPT], pz[PPT], mn[PPT];
    #pragma unroll
    for (int pi = 0; pi < PPT; ++pi) {
        const int p = tile * (PTS * PPT) + pi * PTS + threadIdx.x;
        const float* ap = A + ((size_t)b * N_ + p) * 3;
        px[pi] = ap[0]; py[pi] = ap[1]; pz[pi] = ap[2];
        mn[pi] = FLT_MAX;
    }

    #pragma unroll 4
    for (int j = 0; j < CHUNK; ++j) {
        float4 bv = s[j];
        #pragma unroll
        for (int pi = 0; pi < PPT; ++pi) {
            float dx = px[pi] - bv.x, dy = py[pi] - bv.y, dz = pz[pi] - bv.z;
            mn[pi] = fminf(mn[pi],
                           __fmaf_rn(dx, dx, __fmaf_rn(dy, dy, dz * dz)));
        }
    }

    const size_t ob = (size_t)dir * B_ + b;
    const size_t sm = (ob * JSPLIT + split) * N_;
    #pragma unroll
    for (int pi = 0; pi < PPT; ++pi) {
        const int p = tile * (PTS * PPT) + pi * PTS + threadIdx.x;
        splitmin[sm + p] = __float_as_uint(mn[pi]);   // block-owned store
    }
}

// grid: 2*B_*64 = 512 blocks; blockIdx.x = ((dir*B_+b)<<6)|c64 ; 64 pts/block
__global__ __launch_bounds__(256) void cd_select(
        const float* __restrict__ xyz1, const float* __restrict__ xyz2,
        const unsigned int* __restrict__ splitmin,
        double2* __restrict__ partials, float* __restrict__ out) {
    const int c64 = blockIdx.x & 63;
    const int b   = (blockIdx.x >> 6) & (B_ - 1);
    const int dir = blockIdx.x >> 8;
    const int p0  = c64 * 64;
    const float* A  = dir ? xyz2 : xyz1;
    const float* Bc = dir ? xyz1 : xyz2;
    const double tolk = dir ? TOL_K21 : TOL_K12;
    const size_t ob = (size_t)dir * B_ + b;

    __shared__ unsigned int ltab[64][33];        // padded: conflict-free
    __shared__ unsigned short queue[2048];       // worst case 64*32
    __shared__ unsigned long long dbits[64];
    __shared__ unsigned int pickS[64];
    __shared__ float pc[64][5];                  // x,y,z,a2f,me
    __shared__ unsigned int cnt_total;

    // phase 1: coalesced panel load, transposed store
    #pragma unroll
    for (int k = 0; k < 8; ++k) {
        int idx = threadIdx.x + 256 * k;
        int row = idx >> 6, col = idx & 63;
        ltab[col][row] = splitmin[(ob * JSPLIT + row) * N_ + p0 + col];
    }
    __syncthreads();

    const int t = threadIdx.x;
    // phase 2 (wave 0): per-point m, mask, queue build
    if (t < 64) {
        const int p = p0 + t;
        const float* ap = A + ((size_t)b * N_ + p) * 3;
        const float x = ap[0], y = ap[1], z = ap[2];
        const float a2f = x * x + y * y + z * z;

        float m = FLT_MAX;
        #pragma unroll
        for (int s = 0; s < JSPLIT; ++s)
            m = fminf(m, __uint_as_float(ltab[t][s]));

        const float me = __fmaf_rn(2e-6f, m, m);
        const float skipthr = (me + 7e-7f * a2f) * (1.0f + 4e-6f);

        unsigned int mask = 0;
        #pragma unroll
        for (int s = 0; s < JSPLIT; ++s)
            if (__uint_as_float(ltab[t][s]) <= skipthr) mask |= (1u << s);

        pc[t][0] = x; pc[t][1] = y; pc[t][2] = z; pc[t][3] = a2f; pc[t][4] = me;
        dbits[t] = ~0ULL;
        pickS[t] = 0xFFFFFFFFu;

        unsigned int cnt = (unsigned int)__popc(mask);
        unsigned int pre = cnt;                   // inclusive prefix over 64 lanes
        #pragma unroll
        for (int off = 1; off < 64; off <<= 1) {
            unsigned int o = (unsigned int)__shfl_up((int)pre, off);
            if (t >= off) pre += o;
        }
        unsigned int w = pre - cnt;
        while (mask) {
            int s = __ffs(mask) - 1; mask &= mask - 1;
            queue[w++] = (unsigned short)((t << 5) | s);
        }
        if (t == 63) cnt_total = pre;
    }
    __syncthreads();

    const int wv = t >> 6, lane = t & 63;
    const float* bb = Bc + (size_t)b * N_ * 3;
    const unsigned int ctot = cnt_total;

    // phase 3 pass 1: f64 dmin over prefilter survivors (queue entries)
    for (unsigned int e = wv; e < ctot; e += 4) {
        unsigned int q = queue[e];
        int i = q >> 5, s = q & 31;
        const float x = pc[i][0], y = pc[i][1], z = pc[i][2];
        const float a2f = pc[i][3], me = pc[i][4];
        const double xd = (double)x, yd = (double)y, zd = (double)z;

        double dmin = 1.0e300;
        int j = s * CHUNK + lane;
        #pragma unroll
        for (int k = 0; k < 2; ++k, j += 64) {
            float bx = bb[3 * j], by = bb[3 * j + 1], bz = bb[3 * j + 2];
            float dx = x - bx, dy = y - by, dz = z - bz;
            float d32 = __fmaf_rn(dx, dx, __fmaf_rn(dy, dy, dz * dz));
            float thr = __fmaf_rn(2e-7f, a2f + (bx * bx + by * by + bz * bz), me);
            if (d32 <= thr) {
                double ddx = xd - (double)bx, ddy = yd - (double)by,
                       ddz = zd - (double)bz;
                dmin = fmin(dmin, fma(ddx, ddx, fma(ddy, ddy, ddz * ddz)));
            }
        }
        #pragma unroll
        for (int off = 1; off < 64; off <<= 1)
            dmin = fmin(dmin, __shfl_xor(dmin, off));
        if (lane == 0)
            atomicMin(&dbits[i], (unsigned long long)__double_as_longlong(dmin));
    }
    __syncthreads();

    // phase 3 pass 2: contract pick
    for (unsigned int e = wv; e < ctot; e += 4) {
        unsigned int q = queue[e];
        int i = q >> 5, s = q & 31;
        const float x = pc[i][0], y = pc[i][1], z = pc[i][2];
        const float a2f = pc[i][3], me = pc[i][4];
        const double xd = (double)x, yd = (double)y, zd = (double)z;
        const double a2 = xd * xd + yd * yd + zd * zd;
        const double dminF = __longlong_as_double((long long)dbits[i]);

        unsigned int pick = 0xFFFFFFFFu;
        int j = s * CHUNK + lane;
        #pragma unroll
        for (int k = 0; k < 2; ++k, j += 64) {
            float bx = bb[3 * j], by = bb[3 * j + 1], bz = bb[3 * j + 2];
            float dx = x - bx, dy = y - by, dz = z - bz;
            float d32 = __fmaf_rn(dx, dx, __fmaf_rn(dy, dy, dz * dz));
            float thr = __fmaf_rn(2e-7f, a2f + (bx * bx + by * by + bz * bz), me);
            if (d32 <= thr) {
                double bxd = (double)bx, byd = (double)by, bzd = (double)bz;
                double ddx = xd - bxd, ddy = yd - byd, ddz = zd - bzd;
                double d64 = fma(ddx, ddx, fma(ddy, ddy, ddz * ddz));
                double M   = a2 + (bxd * bxd + byd * byd + bzd * bzd);
                if (d64 <= fma(tolk, M, dminF))
                    pick = (pick < (unsigned int)j) ? pick : (unsigned int)j;
            }
        }
        #pragma unroll
        for (int off = 1; off < 64; off <<= 1) {
            unsigned int o2 = (unsigned int)__shfl_xor((int)pick, off);
            pick = (o2 < pick) ? o2 : pick;
        }
        if (lane == 0) atomicMin(&pickS[i], pick);
    }
    __syncthreads();

    // phase 4 (wave 0): writeback + block loss partial (fixed butterfly order)
    if (t < 64) {
        const size_t obase = (dir == 0) ? (1 + (size_t)b * N_)
                                        : (1 + (size_t)B_ * N_ + (size_t)b * N_);
        out[obase + p0 + t] = (float)pickS[t];

        double dm = __longlong_as_double((long long)dbits[t]);
        double sum = dm, mx = dm;
        #pragma unroll
        for (int off = 1; off < 64; off <<= 1) {
            sum += __shfl_xor(sum, off);
            mx = fmax(mx, __shfl_xor(mx, off));
        }
        if (t == 0) partials[blockIdx.x] = make_double2(sum, mx);
    }
}

// 1 block, 64 threads: fixed-order loss over 512 block partials
__global__ void cd_loss(const double2* __restrict__ partials,
                        float* __restrict__ out) {
    const int lane = threadIdx.x;
    double total = 0.0;
    for (int b = 0; b < B_; ++b) {
        double2 v0 = partials[((0 * B_ + b) << 6) | lane];
        double s12 = v0.x, m12 = v0.y;
        double2 v1 = partials[((1 * B_ + b) << 6) | lane];
        double s21 = v1.x;
        #pragma unroll
        for (int off = 1; off < 64; off <<= 1) {
            s12 += __shfl_xor(s12, off);
            m12 = fmax(m12, __shfl_xor(m12, off));
            s21 += __shfl_xor(s21, off);
        }
        if (lane == 0)
            total += s12 / (double)N_ + BETA_ * m12
                   + (GAMMA_ + DELTA_ * (double)N_) * (s21 / (double)N_);
    }
    if (lane == 0) out[0] = (float)(total / (double)B_);
}

extern "C" void kernel_launch(void* const* d_in, const int* in_sizes, int n_in,
                              void* d_out, int out_size, void* d_ws, size_t ws_size,
                              hipStream_t stream) {
    const float* xyz1 = (const float*)d_in[0];
    const float* xyz2 = (const float*)d_in[1];
    float* out = (float*)d_out;

    const size_t NP = (size_t)2 * B_ * N_;
    double2* partials = (double2*)d_ws;                        // 512 double2
    unsigned int* splitmin = (unsigned int*)(partials + 512);  // NP*JSPLIT (4 MiB)

    dim3 grid(TILES * B_ * 2, JSPLIT);
    cd_min32<<<grid, PTS, 0, stream>>>(xyz1, xyz2, splitmin);

    cd_select<<<2 * B_ * 64, 256, 0, stream>>>(xyz1, xyz2, splitmin,
                                               partials, out);

    cd_loss<<<1, 64, 0, stream>>>(partials, out);
}

// Round 21
// 50.041 us; speedup vs baseline: 1.0213x; 1.0213x over previous
//
#include <hip/hip_runtime.h>
#include <stdint.h>
#include <float.h>

// Chamfer distance, B=4, N=M=4096, 3D fp32.
// Outputs (flat, float32): [0] loss, [1..16384] idx12 (float), [16385..32768] idx21.
//
// SEMANTIC CONTRACT (validated R14-R20, absmax 0.0 — do not change):
//   d in f64: d = fma(dx,dx, fma(dy,dy, dz*dz)), dx = x - bx (f64-promoted f32)
//   pick = smallest index j with d_j <= fma(TOL_K(dir), a2 + b2_j, dmin)
//     (a2, b2_j in f64 from promoted f32 coords)
//   K12 = 0.6*2^-23, K21 = 0.   dmin = exact f64 min.
//   Prefilter (R16-proven 2x margin): survivor iff
//     d32 <= fma(2e-7, a2f+b2f_j, me), me = m*(1+2e-6), m = global f32 min.
//   Split skip (R18-validated): skip iff splitmin > (me + 7e-7*a2f)*(1+4e-6).
//
// R21: cd_min32 drops LDS staging — target address bb[3*j] is wave-uniform
// (loop-index j), so the compiler emits scalar loads through the constant
// cache (L2-resident 192KB cloud) feeding VALU as SGPR operands. Removes
// 1M ds_reads + barrier (~10us LDS-pipe + staging cost). f32 arithmetic
// bit-identical -> splitmin unchanged. cd_select/cd_loss = R20 (passing).

constexpr int B_ = 4;
constexpr int N_ = 4096;
constexpr int PTS = 256;
constexpr int PPT = 2;                   // points per thread (min32)
constexpr int TILES = N_ / (PTS * PPT);  // 8
constexpr int JSPLIT = 32;
constexpr int CHUNK = N_ / JSPLIT;       // 128
constexpr double EPS32 = 1.1920928955078125e-7;  // 2^-23
constexpr double TOL_K12 = 0.6 * EPS32;
constexpr double TOL_K21 = 0.0;
constexpr double BETA_ = 1.0;
constexpr double GAMMA_ = 1.0;
constexpr double DELTA_ = 0.0;

// grid: (TILES*B_*2, JSPLIT)
__global__ __launch_bounds__(256) void cd_min32(
        const float* __restrict__ xyz1, const float* __restrict__ xyz2,
        unsigned int* __restrict__ splitmin) {
    const int tile  = blockIdx.x % TILES;
    const int b     = (blockIdx.x / TILES) % B_;
    const int dir   = blockIdx.x / (TILES * B_);
    const int split = blockIdx.y;
    const float* A  = dir ? xyz2 : xyz1;
    const float* Bc = dir ? xyz1 : xyz2;

    const float* bbase = Bc + ((size_t)b * N_ + (size_t)split * CHUNK) * 3;

    float px[PPT], py[PPT], pz[PPT], mn[PPT];
    #pragma unroll
    for (int pi = 0; pi < PPT; ++pi) {
        const int p = tile * (PTS * PPT) + pi * PTS + threadIdx.x;
        const float* ap = A + ((size_t)b * N_ + p) * 3;
        px[pi] = ap[0]; py[pi] = ap[1]; pz[pi] = ap[2];
        mn[pi] = FLT_MAX;
    }

    #pragma unroll 8
    for (int j = 0; j < CHUNK; ++j) {
        // wave-uniform address -> scalar (constant-cache) loads, no LDS
        const float bx = bbase[3 * j + 0];
        const float by = bbase[3 * j + 1];
        const float bz = bbase[3 * j + 2];
        #pragma unroll
        for (int pi = 0; pi < PPT; ++pi) {
            float dx = px[pi] - bx, dy = py[pi] - by, dz = pz[pi] - bz;
            mn[pi] = fminf(mn[pi],
                           __fmaf_rn(dx, dx, __fmaf_rn(dy, dy, dz * dz)));
        }
    }

    const size_t ob = (size_t)dir * B_ + b;
    const size_t sm = (ob * JSPLIT + split) * N_;
    #pragma unroll
    for (int pi = 0; pi < PPT; ++pi) {
        const int p = tile * (PTS * PPT) + pi * PTS + threadIdx.x;
        splitmin[sm + p] = __float_as_uint(mn[pi]);   // block-owned store
    }
}

// grid: 2*B_*64 = 512 blocks; blockIdx.x = ((dir*B_+b)<<6)|c64 ; 64 pts/block
__global__ __launch_bounds__(256) void cd_select(
        const float* __restrict__ xyz1, const float* __restrict__ xyz2,
        const unsigned int* __restrict__ splitmin,
        double2* __restrict__ partials, float* __restrict__ out) {
    const int c64 = blockIdx.x & 63;
    const int b   = (blockIdx.x >> 6) & (B_ - 1);
    const int dir = blockIdx.x >> 8;
    const int p0  = c64 * 64;
    const float* A  = dir ? xyz2 : xyz1;
    const float* Bc = dir ? xyz1 : xyz2;
    const double tolk = dir ? TOL_K21 : TOL_K12;
    const size_t ob = (size_t)dir * B_ + b;

    __shared__ unsigned int ltab[64][33];        // padded: conflict-free
    __shared__ unsigned short queue[2048];       // worst case 64*32
    __shared__ unsigned long long dbits[64];
    __shared__ unsigned int pickS[64];
    __shared__ float pc[64][5];                  // x,y,z,a2f,me
    __shared__ unsigned int cnt_total;

    // phase 1: coalesced panel load, transposed store
    #pragma unroll
    for (int k = 0; k < 8; ++k) {
        int idx = threadIdx.x + 256 * k;
        int row = idx >> 6, col = idx & 63;
        ltab[col][row] = splitmin[(ob * JSPLIT + row) * N_ + p0 + col];
    }
    __syncthreads();

    const int t = threadIdx.x;
    // phase 2 (wave 0): per-point m, mask, queue build
    if (t < 64) {
        const int p = p0 + t;
        const float* ap = A + ((size_t)b * N_ + p) * 3;
        const float x = ap[0], y = ap[1], z = ap[2];
        const float a2f = x * x + y * y + z * z;

        float m = FLT_MAX;
        #pragma unroll
        for (int s = 0; s < JSPLIT; ++s)
            m = fminf(m, __uint_as_float(ltab[t][s]));

        const float me = __fmaf_rn(2e-6f, m, m);
        const float skipthr = (me + 7e-7f * a2f) * (1.0f + 4e-6f);

        unsigned int mask = 0;
        #pragma unroll
        for (int s = 0; s < JSPLIT; ++s)
            if (__uint_as_float(ltab[t][s]) <= skipthr) mask |= (1u << s);

        pc[t][0] = x; pc[t][1] = y; pc[t][2] = z; pc[t][3] = a2f; pc[t][4] = me;
        dbits[t] = ~0ULL;
        pickS[t] = 0xFFFFFFFFu;

        unsigned int cnt = (unsigned int)__popc(mask);
        unsigned int pre = cnt;                   // inclusive prefix over 64 lanes
        #pragma unroll
        for (int off = 1; off < 64; off <<= 1) {
            unsigned int o = (unsigned int)__shfl_up((int)pre, off);
            if (t >= off) pre += o;
        }
        unsigned int w = pre - cnt;
        while (mask) {
            int s = __ffs(mask) - 1; mask &= mask - 1;
            queue[w++] = (unsigned short)((t << 5) | s);
        }
        if (t == 63) cnt_total = pre;
    }
    __syncthreads();

    const int wv = t >> 6, lane = t & 63;
    const float* bb = Bc + (size_t)b * N_ * 3;
    const unsigned int ctot = cnt_total;

    // phase 3 pass 1: f64 dmin over prefilter survivors (queue entries)
    for (unsigned int e = wv; e < ctot; e += 4) {
        unsigned int q = queue[e];
        int i = q >> 5, s = q & 31;
        const float x = pc[i][0], y = pc[i][1], z = pc[i][2];
        const float a2f = pc[i][3], me = pc[i][4];
        const double xd = (double)x, yd = (double)y, zd = (double)z;

        double dmin = 1.0e300;
        int j = s * CHUNK + lane;
        #pragma unroll
        for (int k = 0; k < 2; ++k, j += 64) {
            float bx = bb[3 * j], by = bb[3 * j + 1], bz = bb[3 * j + 2];
            float dx = x - bx, dy = y - by, dz = z - bz;
            float d32 = __fmaf_rn(dx, dx, __fmaf_rn(dy, dy, dz * dz));
            float thr = __fmaf_rn(2e-7f, a2f + (bx * bx + by * by + bz * bz), me);
            if (d32 <= thr) {
                double ddx = xd - (double)bx, ddy = yd - (double)by,
                       ddz = zd - (double)bz;
                dmin = fmin(dmin, fma(ddx, ddx, fma(ddy, ddy, ddz * ddz)));
            }
        }
        #pragma unroll
        for (int off = 1; off < 64; off <<= 1)
            dmin = fmin(dmin, __shfl_xor(dmin, off));
        if (lane == 0)
            atomicMin(&dbits[i], (unsigned long long)__double_as_longlong(dmin));
    }
    __syncthreads();

    // phase 3 pass 2: contract pick
    for (unsigned int e = wv; e < ctot; e += 4) {
        unsigned int q = queue[e];
        int i = q >> 5, s = q & 31;
        const float x = pc[i][0], y = pc[i][1], z = pc[i][2];
        const float a2f = pc[i][3], me = pc[i][4];
        const double xd = (double)x, yd = (double)y, zd = (double)z;
        const double a2 = xd * xd + yd * yd + zd * zd;
        const double dminF = __longlong_as_double((long long)dbits[i]);

        unsigned int pick = 0xFFFFFFFFu;
        int j = s * CHUNK + lane;
        #pragma unroll
        for (int k = 0; k < 2; ++k, j += 64) {
            float bx = bb[3 * j], by = bb[3 * j + 1], bz = bb[3 * j + 2];
            float dx = x - bx, dy = y - by, dz = z - bz;
            float d32 = __fmaf_rn(dx, dx, __fmaf_rn(dy, dy, dz * dz));
            float thr = __fmaf_rn(2e-7f, a2f + (bx * bx + by * by + bz * bz), me);
            if (d32 <= thr) {
                double bxd = (double)bx, byd = (double)by, bzd = (double)bz;
                double ddx = xd - bxd, ddy = yd - byd, ddz = zd - bzd;
                double d64 = fma(ddx, ddx, fma(ddy, ddy, ddz * ddz));
                double M   = a2 + (bxd * bxd + byd * byd + bzd * bzd);
                if (d64 <= fma(tolk, M, dminF))
                    pick = (pick < (unsigned int)j) ? pick : (unsigned int)j;
            }
        }
        #pragma unroll
        for (int off = 1; off < 64; off <<= 1) {
            unsigned int o2 = (unsigned int)__shfl_xor((int)pick, off);
            pick = (o2 < pick) ? o2 : pick;
        }
        if (lane == 0) atomicMin(&pickS[i], pick);
    }
    __syncthreads();

    // phase 4 (wave 0): writeback + block loss partial (fixed butterfly order)
    if (t < 64) {
        const size_t obase = (dir == 0) ? (1 + (size_t)b * N_)
                                        : (1 + (size_t)B_ * N_ + (size_t)b * N_);
        out[obase + p0 + t] = (float)pickS[t];

        double dm = __longlong_as_double((long long)dbits[t]);
        double sum = dm, mx = dm;
        #pragma unroll
        for (int off = 1; off < 64; off <<= 1) {
            sum += __shfl_xor(sum, off);
            mx = fmax(mx, __shfl_xor(mx, off));
        }
        if (t == 0) partials[blockIdx.x] = make_double2(sum, mx);
    }
}

// 1 block, 64 threads: fixed-order loss over 512 block partials
__global__ void cd_loss(const double2* __restrict__ partials,
                        float* __restrict__ out) {
    const int lane = threadIdx.x;
    double total = 0.0;
    for (int b = 0; b < B_; ++b) {
        double2 v0 = partials[((0 * B_ + b) << 6) | lane];
        double s12 = v0.x, m12 = v0.y;
        double2 v1 = partials[((1 * B_ + b) << 6) | lane];
        double s21 = v1.x;
        #pragma unroll
        for (int off = 1; off < 64; off <<= 1) {
            s12 += __shfl_xor(s12, off);
            m12 = fmax(m12, __shfl_xor(m12, off));
            s21 += __shfl_xor(s21, off);
        }
        if (lane == 0)
            total += s12 / (double)N_ + BETA_ * m12
                   + (GAMMA_ + DELTA_ * (double)N_) * (s21 / (double)N_);
    }
    if (lane == 0) out[0] = (float)(total / (double)B_);
}

extern "C" void kernel_launch(void* const* d_in, const int* in_sizes, int n_in,
                              void* d_out, int out_size, void* d_ws, size_t ws_size,
                              hipStream_t stream) {
    const float* xyz1 = (const float*)d_in[0];
    const float* xyz2 = (const float*)d_in[1];
    float* out = (float*)d_out;

    double2* partials = (double2*)d_ws;                        // 512 double2
    unsigned int* splitmin = (unsigned int*)(partials + 512);  // NP*JSPLIT (4 MiB)

    dim3 grid(TILES * B_ * 2, JSPLIT);
    cd_min32<<<grid, PTS, 0, stream>>>(xyz1, xyz2, splitmin);

    cd_select<<<2 * B_ * 64, 256, 0, stream>>>(xyz1, xyz2, splitmin,
                                               partials, out);

    cd_loss<<<1, 64, 0, stream>>>(partials, out);
}